// Round 1
// baseline (760.832 us; speedup 1.0000x reference)
//
#include <hip/hip_runtime.h>
#include <math.h>

#define B_ 32
#define S_ 4096
#define H_ 1024
#define T_ 512
#define OUTK_ (2*H_ + T_)   // 2560

// ---------------------------------------------------------------------------
// K1: gamma[b,i] = b_in[i] + dot(x[b,:], W_in[i,:])
// wave per (i, b-half): W_in row fragment held in 4 float4 regs, 16 b's looped.
// ---------------------------------------------------------------------------
__global__ __launch_bounds__(256) void k_gamma(const float* __restrict__ x,
                                               const float* __restrict__ W_in,
                                               const float* __restrict__ b_in,
                                               float* __restrict__ gamma) {
    int lane = threadIdx.x & 63;
    int wid  = blockIdx.x * 4 + (threadIdx.x >> 6);   // 0..2047
    int i    = wid >> 1;                               // 0..1023
    int b0   = (wid & 1) * 16;
    const float4* Wr = (const float4*)(W_in + (size_t)i * H_);
    float4 wf[4];
    #pragma unroll
    for (int k = 0; k < 4; ++k) wf[k] = Wr[k*64 + lane];
    float bias = b_in[i];
    for (int bb = 0; bb < 16; ++bb) {
        int b = b0 + bb;
        const float4* xr = (const float4*)(x + (size_t)b * H_);
        float p = 0.f;
        #pragma unroll
        for (int k = 0; k < 4; ++k) {
            float4 v = xr[k*64 + lane];
            p += v.x*wf[k].x + v.y*wf[k].y + v.z*wf[k].z + v.w*wf[k].w;
        }
        #pragma unroll
        for (int off = 32; off >= 1; off >>= 1) p += __shfl_xor(p, off, 64);
        if (lane == 0) gamma[(size_t)b * H_ + i] = p + bias;
    }
}

// ---------------------------------------------------------------------------
// K2 (the big one): single pass over context.
// wave per (b, s-chunk): for each row s -> score = <ctx_row, gamma_b>,
// write raw score, then online-softmax update of (m, l, acc[1024]) with the
// row still in registers. Partials written to ws.
// Coalescing: reg k of lane holds floats [k*256 + lane*4 .. +3] -> every
// global_load_dwordx4 covers 1 KiB contiguous.
// ---------------------------------------------------------------------------
__global__ __launch_bounds__(256) void k_scores_online(const float* __restrict__ context,
                                                       const float* __restrict__ gamma,
                                                       float* __restrict__ scores,
                                                       float* __restrict__ pm,
                                                       float* __restrict__ pl,
                                                       float* __restrict__ pacc,
                                                       int WPB, int rows) {
    int lane = threadIdx.x & 63;
    int b    = blockIdx.y;
    int wave = blockIdx.x * 4 + (threadIdx.x >> 6);   // 0..WPB-1

    const float4* gr = (const float4*)(gamma + (size_t)b * H_);
    float4 g[4];
    #pragma unroll
    for (int k = 0; k < 4; ++k) g[k] = gr[k*64 + lane];

    const float4* ctx = (const float4*)(context + (size_t)b * S_ * H_);
    float  m = -INFINITY, l = 0.f;
    float4 acc[4];
    #pragma unroll
    for (int k = 0; k < 4; ++k) acc[k] = make_float4(0.f, 0.f, 0.f, 0.f);

    int s0 = wave * rows;
    for (int s = s0; s < s0 + rows; ++s) {
        float4 c[4];
        #pragma unroll
        for (int k = 0; k < 4; ++k) c[k] = ctx[(size_t)s*256 + k*64 + lane];
        float p = 0.f;
        #pragma unroll
        for (int k = 0; k < 4; ++k)
            p += c[k].x*g[k].x + c[k].y*g[k].y + c[k].z*g[k].z + c[k].w*g[k].w;
        #pragma unroll
        for (int off = 32; off >= 1; off >>= 1) p += __shfl_xor(p, off, 64);
        if (lane == 0) scores[(size_t)b*S_ + s] = p;

        float mnew  = fmaxf(m, p);
        float scale = __expf(m - mnew);   // first iter: exp(-inf) = 0
        float w     = __expf(p - mnew);
        l = l * scale + w;
        #pragma unroll
        for (int k = 0; k < 4; ++k) {
            acc[k].x = acc[k].x*scale + w*c[k].x;
            acc[k].y = acc[k].y*scale + w*c[k].y;
            acc[k].z = acc[k].z*scale + w*c[k].z;
            acc[k].w = acc[k].w*scale + w*c[k].w;
        }
        m = mnew;
    }

    int pw = b * WPB + wave;
    if (lane == 0) { pm[pw] = m; pl[pw] = l; }
    float4* pa = (float4*)(pacc + (size_t)pw * H_);
    #pragma unroll
    for (int k = 0; k < 4; ++k) pa[k*64 + lane] = acc[k];
}

// ---------------------------------------------------------------------------
// K3a: c_t[b,h] = (1/L) * sum_w exp(m_w - M) * acc_w[h]
// block per (h-tile of 256, b); M,L recomputed in-block from partials.
// ---------------------------------------------------------------------------
__global__ __launch_bounds__(256) void k_ct(const float* __restrict__ pm,
                                            const float* __restrict__ pl,
                                            const float* __restrict__ pacc,
                                            float* __restrict__ ct,
                                            int WPB) {
    __shared__ float red[128];
    __shared__ float ew[128];
    int tid = threadIdx.x;
    int b   = blockIdx.y;

    float mv = -INFINITY;
    if (tid < WPB) mv = pm[b*WPB + tid];
    if (tid < 128) red[tid] = mv;
    __syncthreads();
    for (int st = 64; st >= 1; st >>= 1) {
        if (tid < st) red[tid] = fmaxf(red[tid], red[tid + st]);
        __syncthreads();
    }
    float M = red[0];
    __syncthreads();

    float term = 0.f;
    if (tid < WPB) {
        float e = __expf(pm[b*WPB + tid] - M);
        ew[tid] = e;
        term = pl[b*WPB + tid] * e;
    }
    if (tid < 128) red[tid] = term;
    __syncthreads();
    for (int st = 64; st >= 1; st >>= 1) {
        if (tid < st) red[tid] += red[tid + st];
        __syncthreads();
    }
    float invL = 1.f / red[0];

    int h = blockIdx.x * 256 + tid;
    float c = 0.f;
    for (int w = 0; w < WPB; ++w)
        c += ew[w] * pacc[(size_t)(b*WPB + w) * H_ + h];
    ct[(size_t)b*H_ + h] = c * invL;
}

// ---------------------------------------------------------------------------
// K3b: weights[b,s] = exp(scores[b,s] - M) / L   (written straight to d_out)
// ---------------------------------------------------------------------------
__global__ __launch_bounds__(256) void k_weights(const float* __restrict__ pm,
                                                 const float* __restrict__ pl,
                                                 const float* __restrict__ scores,
                                                 float* __restrict__ wout,
                                                 int WPB) {
    __shared__ float red[128];
    int tid = threadIdx.x;
    int b   = blockIdx.y;

    float mv = -INFINITY;
    if (tid < WPB) mv = pm[b*WPB + tid];
    if (tid < 128) red[tid] = mv;
    __syncthreads();
    for (int st = 64; st >= 1; st >>= 1) {
        if (tid < st) red[tid] = fmaxf(red[tid], red[tid + st]);
        __syncthreads();
    }
    float M = red[0];
    __syncthreads();

    float term = (tid < WPB) ? pl[b*WPB + tid] * __expf(pm[b*WPB + tid] - M) : 0.f;
    if (tid < 128) red[tid] = term;
    __syncthreads();
    for (int st = 64; st >= 1; st >>= 1) {
        if (tid < st) red[tid] += red[tid + st];
        __syncthreads();
    }
    float invL = 1.f / red[0];

    int s = blockIdx.x * 256 + tid;
    wout[(size_t)b*S_ + s] = __expf(scores[(size_t)b*S_ + s] - M) * invL;
}

// ---------------------------------------------------------------------------
// K4: out[b,i] = tanh(b_out[i] + dot(cat[b,:], W_out[i,:])),
// cat = [c_t | x | topic] read piecewise (never materialized).
// wave per (i, b-half); W_out row (10 float4) held in regs across 16 b's.
// ---------------------------------------------------------------------------
__global__ __launch_bounds__(256) void k_out(const float* __restrict__ ct,
                                             const float* __restrict__ x,
                                             const float* __restrict__ topic,
                                             const float* __restrict__ W_out,
                                             const float* __restrict__ b_out,
                                             float* __restrict__ out) {
    int lane = threadIdx.x & 63;
    int wid  = blockIdx.x * 4 + (threadIdx.x >> 6);   // 0..2047
    int i    = wid >> 1;
    int b0   = (wid & 1) * 16;
    const float4* Wr = (const float4*)(W_out + (size_t)i * OUTK_);
    float4 wf[10];
    #pragma unroll
    for (int k = 0; k < 10; ++k) wf[k] = Wr[k*64 + lane];
    float bias = b_out[i];
    for (int bb = 0; bb < 16; ++bb) {
        int b = b0 + bb;
        const float4* cr = (const float4*)(ct    + (size_t)b*H_);
        const float4* xr = (const float4*)(x     + (size_t)b*H_);
        const float4* tr = (const float4*)(topic + (size_t)b*T_);
        float p = 0.f;
        #pragma unroll
        for (int k = 0; k < 4; ++k) {
            float4 v = cr[k*64 + lane];
            p += v.x*wf[k].x + v.y*wf[k].y + v.z*wf[k].z + v.w*wf[k].w;
        }
        #pragma unroll
        for (int k = 0; k < 4; ++k) {
            float4 v = xr[k*64 + lane];
            p += v.x*wf[4+k].x + v.y*wf[4+k].y + v.z*wf[4+k].z + v.w*wf[4+k].w;
        }
        #pragma unroll
        for (int k = 0; k < 2; ++k) {
            float4 v = tr[k*64 + lane];
            p += v.x*wf[8+k].x + v.y*wf[8+k].y + v.z*wf[8+k].z + v.w*wf[8+k].w;
        }
        #pragma unroll
        for (int off = 32; off >= 1; off >>= 1) p += __shfl_xor(p, off, 64);
        if (lane == 0) out[(size_t)b*H_ + i] = tanhf(p + bias);
    }
}

// ---------------------------------------------------------------------------
extern "C" void kernel_launch(void* const* d_in, const int* in_sizes, int n_in,
                              void* d_out, int out_size, void* d_ws, size_t ws_size,
                              hipStream_t stream) {
    const float* x       = (const float*)d_in[0];
    const float* context = (const float*)d_in[1];
    const float* topic   = (const float*)d_in[2];
    const float* W_in    = (const float*)d_in[3];
    const float* b_in    = (const float*)d_in[4];
    const float* W_out   = (const float*)d_in[5];
    const float* b_out   = (const float*)d_in[6];

    float* out     = (float*)d_out;          // [B,H] = 32768 floats
    float* weights = out + (size_t)B_ * H_;  // [B,S] = 131072 floats

    // Pick waves-per-batch so partials fit in workspace (prefer 128).
    int WPB = 128;
    while (WPB > 4) {
        size_t need = ((size_t)(B_*H_ + B_*S_ + B_*H_) +
                       (size_t)B_ * WPB * (2 + H_)) * sizeof(float);
        if (need <= ws_size) break;
        WPB >>= 1;
    }
    int rows = S_ / WPB;

    float* ws     = (float*)d_ws;
    float* gamma  = ws;                        // B*H
    float* scores = gamma  + (size_t)B_ * H_;  // B*S
    float* ct     = scores + (size_t)B_ * S_;  // B*H
    float* pm     = ct     + (size_t)B_ * H_;  // B*WPB
    float* pl     = pm     + (size_t)B_ * WPB; // B*WPB
    float* pacc   = pl     + (size_t)B_ * WPB; // B*WPB*H

    hipLaunchKernelGGL(k_gamma, dim3(512), dim3(256), 0, stream,
                       x, W_in, b_in, gamma);
    hipLaunchKernelGGL(k_scores_online, dim3(WPB/4, B_), dim3(256), 0, stream,
                       context, gamma, scores, pm, pl, pacc, WPB, rows);
    hipLaunchKernelGGL(k_ct, dim3(H_/256, B_), dim3(256), 0, stream,
                       pm, pl, pacc, ct, WPB);
    hipLaunchKernelGGL(k_weights, dim3(S_/256, B_), dim3(256), 0, stream,
                       pm, pl, scores, weights, WPB);
    hipLaunchKernelGGL(k_out, dim3(512), dim3(256), 0, stream,
                       ct, x, topic, W_out, b_out, out);
}

// Round 2
// 759.370 us; speedup vs baseline: 1.0019x; 1.0019x over previous
//
#include <hip/hip_runtime.h>
#include <math.h>

#define B_ 32
#define S_ 4096
#define H_ 1024
#define T_ 512
#define OUTK_ (2*H_ + T_)   // 2560
#define WPB_ 128            // waves per batch in k_scores_online
#define ROWS_ (S_ / WPB_)   // 32 rows per wave

// ---------------------------------------------------------------------------
// K1: gamma[b,i] = b_in[i] + dot(x[b,:], W_in[i,:])
// wave per (i, b-half): W_in row fragment held in 4 float4 regs, 16 b's looped.
// ---------------------------------------------------------------------------
__global__ __launch_bounds__(256) void k_gamma(const float* __restrict__ x,
                                               const float* __restrict__ W_in,
                                               const float* __restrict__ b_in,
                                               float* __restrict__ gamma) {
    int lane = threadIdx.x & 63;
    int wid  = blockIdx.x * 4 + (threadIdx.x >> 6);   // 0..2047
    int i    = wid >> 1;                               // 0..1023
    int b0   = (wid & 1) * 16;
    const float4* Wr = (const float4*)(W_in + (size_t)i * H_);
    float4 wf[4];
    #pragma unroll
    for (int k = 0; k < 4; ++k) wf[k] = Wr[k*64 + lane];
    float bias = b_in[i];
    for (int bb = 0; bb < 16; ++bb) {
        int b = b0 + bb;
        const float4* xr = (const float4*)(x + (size_t)b * H_);
        float p = 0.f;
        #pragma unroll
        for (int k = 0; k < 4; ++k) {
            float4 v = xr[k*64 + lane];
            p += v.x*wf[k].x + v.y*wf[k].y + v.z*wf[k].z + v.w*wf[k].w;
        }
        #pragma unroll
        for (int off = 32; off >= 1; off >>= 1) p += __shfl_xor(p, off, 64);
        if (lane == 0) gamma[(size_t)b * H_ + i] = p + bias;
    }
}

// ---------------------------------------------------------------------------
// K2: single pass over context (512 MB — the roofline term).
// wave per (b, 32-row chunk). 2-row unroll: two independent dot+butterfly
// chains in flight, one shared rescale of the online accumulator.
// Lane k-reg layout -> every global_load_dwordx4 covers 1 KiB contiguous.
// ---------------------------------------------------------------------------
__global__ __launch_bounds__(256) void k_scores_online(const float* __restrict__ context,
                                                       const float* __restrict__ gamma,
                                                       float* __restrict__ scores,
                                                       float* __restrict__ pm,
                                                       float* __restrict__ pl,
                                                       float* __restrict__ pacc) {
    int lane = threadIdx.x & 63;
    int b    = blockIdx.y;
    int wave = blockIdx.x * 4 + (threadIdx.x >> 6);   // 0..WPB_-1

    const float4* gr = (const float4*)(gamma + (size_t)b * H_);
    float4 g[4];
    #pragma unroll
    for (int k = 0; k < 4; ++k) g[k] = gr[k*64 + lane];

    const float4* ctx = (const float4*)(context + (size_t)b * S_ * H_);
    float  m = -INFINITY, l = 0.f;
    float4 acc[4];
    #pragma unroll
    for (int k = 0; k < 4; ++k) acc[k] = make_float4(0.f, 0.f, 0.f, 0.f);

    int s0 = wave * ROWS_;
    for (int s = s0; s < s0 + ROWS_; s += 2) {
        float4 c0[4], c1[4];
        #pragma unroll
        for (int k = 0; k < 4; ++k) c0[k] = ctx[(size_t)s*256 + k*64 + lane];
        #pragma unroll
        for (int k = 0; k < 4; ++k) c1[k] = ctx[(size_t)(s+1)*256 + k*64 + lane];

        float p0 = 0.f, p1 = 0.f;
        #pragma unroll
        for (int k = 0; k < 4; ++k) {
            p0 += c0[k].x*g[k].x + c0[k].y*g[k].y + c0[k].z*g[k].z + c0[k].w*g[k].w;
            p1 += c1[k].x*g[k].x + c1[k].y*g[k].y + c1[k].z*g[k].z + c1[k].w*g[k].w;
        }
        #pragma unroll
        for (int off = 32; off >= 1; off >>= 1) {
            p0 += __shfl_xor(p0, off, 64);
            p1 += __shfl_xor(p1, off, 64);
        }
        if (lane == 0) {
            scores[(size_t)b*S_ + s]     = p0;
            scores[(size_t)b*S_ + s + 1] = p1;
        }

        float mnew  = fmaxf(m, fmaxf(p0, p1));
        float scale = __expf(m  - mnew);   // first iter: exp(-inf) = 0
        float w0    = __expf(p0 - mnew);
        float w1    = __expf(p1 - mnew);
        l = l * scale + w0 + w1;
        #pragma unroll
        for (int k = 0; k < 4; ++k) {
            acc[k].x = acc[k].x*scale + w0*c0[k].x + w1*c1[k].x;
            acc[k].y = acc[k].y*scale + w0*c0[k].y + w1*c1[k].y;
            acc[k].z = acc[k].z*scale + w0*c0[k].z + w1*c1[k].z;
            acc[k].w = acc[k].w*scale + w0*c0[k].w + w1*c1[k].w;
        }
        m = mnew;
    }

    int pw = b * WPB_ + wave;
    if (lane == 0) { pm[pw] = m; pl[pw] = l; }
    float4* pa = (float4*)(pacc + (size_t)pw * H_);
    #pragma unroll
    for (int k = 0; k < 4; ++k) pa[k*64 + lane] = acc[k];
}

// ---------------------------------------------------------------------------
// K3: finalize. Every block redoes the cheap 128-wide M/L reduction from the
// per-wave partials, then:
//   blocks x <  H_/256 : c_t tile  (combine pacc partials)
//   blocks x >= H_/256 : weights tile (exp(score - M)/L -> d_out)
// ---------------------------------------------------------------------------
__global__ __launch_bounds__(256) void k_finalize(const float* __restrict__ pm,
                                                  const float* __restrict__ pl,
                                                  const float* __restrict__ pacc,
                                                  const float* __restrict__ scores,
                                                  float* __restrict__ ct,
                                                  float* __restrict__ wout) {
    __shared__ float red[128];
    __shared__ float ew[WPB_];
    int tid = threadIdx.x;
    int b   = blockIdx.y;

    float mv = (tid < WPB_) ? pm[b*WPB_ + tid] : -INFINITY;
    if (tid < 128) red[tid] = mv;
    __syncthreads();
    for (int st = 64; st >= 1; st >>= 1) {
        if (tid < st) red[tid] = fmaxf(red[tid], red[tid + st]);
        __syncthreads();
    }
    float M = red[0];
    __syncthreads();

    float term = 0.f;
    if (tid < WPB_) {
        float e = __expf(pm[b*WPB_ + tid] - M);
        ew[tid] = e;
        term = pl[b*WPB_ + tid] * e;
    }
    if (tid < 128) red[tid] = term;
    __syncthreads();
    for (int st = 64; st >= 1; st >>= 1) {
        if (tid < st) red[tid] += red[tid + st];
        __syncthreads();
    }
    float invL = 1.f / red[0];

    if (blockIdx.x < H_/256) {
        int h = blockIdx.x * 256 + tid;
        float c = 0.f;
        for (int w = 0; w < WPB_; ++w)
            c += ew[w] * pacc[(size_t)(b*WPB_ + w) * H_ + h];
        ct[(size_t)b*H_ + h] = c * invL;
    } else {
        int s = (blockIdx.x - H_/256) * 256 + tid;
        wout[(size_t)b*S_ + s] = __expf(scores[(size_t)b*S_ + s] - M) * invL;
    }
}

// ---------------------------------------------------------------------------
// K4: out[b,i] = tanh(b_out[i] + dot([c_t|x|topic], W_out[i,:]))
// wave per (i, b-half); W_out row (10 float4) held in regs across 16 b's.
// ---------------------------------------------------------------------------
__global__ __launch_bounds__(256) void k_out(const float* __restrict__ ct,
                                             const float* __restrict__ x,
                                             const float* __restrict__ topic,
                                             const float* __restrict__ W_out,
                                             const float* __restrict__ b_out,
                                             float* __restrict__ out) {
    int lane = threadIdx.x & 63;
    int wid  = blockIdx.x * 4 + (threadIdx.x >> 6);   // 0..2047
    int i    = wid >> 1;
    int b0   = (wid & 1) * 16;
    const float4* Wr = (const float4*)(W_out + (size_t)i * OUTK_);
    float4 wf[10];
    #pragma unroll
    for (int k = 0; k < 10; ++k) wf[k] = Wr[k*64 + lane];
    float bias = b_out[i];
    for (int bb = 0; bb < 16; ++bb) {
        int b = b0 + bb;
        const float4* cr = (const float4*)(ct    + (size_t)b*H_);
        const float4* xr = (const float4*)(x     + (size_t)b*H_);
        const float4* tr = (const float4*)(topic + (size_t)b*T_);
        float p = 0.f;
        #pragma unroll
        for (int k = 0; k < 4; ++k) {
            float4 v = cr[k*64 + lane];
            p += v.x*wf[k].x + v.y*wf[k].y + v.z*wf[k].z + v.w*wf[k].w;
        }
        #pragma unroll
        for (int k = 0; k < 4; ++k) {
            float4 v = xr[k*64 + lane];
            p += v.x*wf[4+k].x + v.y*wf[4+k].y + v.z*wf[4+k].z + v.w*wf[4+k].w;
        }
        #pragma unroll
        for (int k = 0; k < 2; ++k) {
            float4 v = tr[k*64 + lane];
            p += v.x*wf[8+k].x + v.y*wf[8+k].y + v.z*wf[8+k].z + v.w*wf[8+k].w;
        }
        #pragma unroll
        for (int off = 32; off >= 1; off >>= 1) p += __shfl_xor(p, off, 64);
        if (lane == 0) out[(size_t)b*H_ + i] = tanhf(p + bias);
    }
}

// ---------------------------------------------------------------------------
extern "C" void kernel_launch(void* const* d_in, const int* in_sizes, int n_in,
                              void* d_out, int out_size, void* d_ws, size_t ws_size,
                              hipStream_t stream) {
    const float* x       = (const float*)d_in[0];
    const float* context = (const float*)d_in[1];
    const float* topic   = (const float*)d_in[2];
    const float* W_in    = (const float*)d_in[3];
    const float* b_in    = (const float*)d_in[4];
    const float* W_out   = (const float*)d_in[5];
    const float* b_out   = (const float*)d_in[6];

    float* out     = (float*)d_out;          // [B,H] = 32768 floats
    float* weights = out + (size_t)B_ * H_;  // [B,S] = 131072 floats

    float* ws     = (float*)d_ws;
    float* gamma  = ws;                         // B*H
    float* scores = gamma  + (size_t)B_ * H_;   // B*S
    float* ct     = scores + (size_t)B_ * S_;   // B*H
    float* pm     = ct     + (size_t)B_ * H_;   // B*WPB_
    float* pl     = pm     + (size_t)B_ * WPB_; // B*WPB_
    float* pacc   = pl     + (size_t)B_ * WPB_; // B*WPB_*H  (~16.8 MB; ws is 2 GiB)

    hipLaunchKernelGGL(k_gamma, dim3(512), dim3(256), 0, stream,
                       x, W_in, b_in, gamma);
    hipLaunchKernelGGL(k_scores_online, dim3(WPB_/4, B_), dim3(256), 0, stream,
                       context, gamma, scores, pm, pl, pacc);
    hipLaunchKernelGGL(k_finalize, dim3(H_/256 + S_/256, B_), dim3(256), 0, stream,
                       pm, pl, pacc, scores, ct, weights);
    hipLaunchKernelGGL(k_out, dim3(512), dim3(256), 0, stream,
                       ct, x, topic, W_out, b_out, out);
}